// Round 4
// baseline (9020.768 us; speedup 1.0000x reference)
//
#include <hip/hip_runtime.h>
#include <stdint.h>

#define NPTS  2048
#define BATCH 2
#define KNN   128
#define C1    128
#define C2    256
#define C3    512
#define C4    128
#define JC    16
#define PAD   20
#define NCHUNK (KNN / JC)        // 8
#define NGROUP (BATCH * NPTS)    // 4096
#define FEAT_ELEMS (BATCH * C4 * NPTS)  // 524288
#define HBINS 2048
#define NREP  8

typedef short short8 __attribute__((ext_vector_type(8)));
typedef float float4v __attribute__((ext_vector_type(4)));
#define MFMA16(a, b, c) __builtin_amdgcn_mfma_f32_16x16x32_bf16(a, b, c, 0, 0, 0)

__device__ __host__ inline unsigned short f2bf(float x) {
    unsigned u = __float_as_uint(x);
    return (unsigned short)((u + 0x7fffu + ((u >> 16) & 1u)) >> 16);
}
__device__ inline float bf2f(unsigned short s) {
    return __uint_as_float(((unsigned)s) << 16);
}

// ---------------------------------------------------------------------------
// prep: fp32 transposes for stats2 + bf16 hi/lo weight planes for MFMA final.
// w3b = w3[:, 256:512] (the f2 half), [m][k] k-contiguous.
__global__ void prep_kernel(const float* __restrict__ w2, const float* __restrict__ w3,
                            const float* __restrict__ w4,
                            float* __restrict__ w2t, float* __restrict__ w3t,
                            unsigned short* __restrict__ w2hg, unsigned short* __restrict__ w2lg,
                            unsigned short* __restrict__ w3bh, unsigned short* __restrict__ w3bl,
                            unsigned short* __restrict__ w4hg, unsigned short* __restrict__ w4lg) {
    int tid = blockIdx.x * blockDim.x + threadIdx.x;
    int stride = gridDim.x * blockDim.x;
    for (int i = tid; i < C2 * C1; i += stride) {
        float v = w2[i];
        w2t[(i & (C1 - 1)) * C2 + (i >> 7)] = v;
        unsigned short h = f2bf(v);
        w2hg[i] = h; w2lg[i] = f2bf(v - bf2f(h));
    }
    for (int i = tid; i < C3 * C3; i += stride) w3t[(i & (C3 - 1)) * C3 + (i >> 9)] = w3[i];
    for (int i = tid; i < C3 * C2; i += stride) {
        int m = i >> 8, k = i & 255;
        float v = w3[m * C3 + C2 + k];
        unsigned short h = f2bf(v);
        w3bh[i] = h; w3bl[i] = f2bf(v - bf2f(h));
    }
    for (int i = tid; i < C4 * C3; i += stride) {
        float v = w4[i];
        unsigned short h = f2bf(v);
        w4hg[i] = h; w4lg[i] = f2bf(v - bf2f(h));
    }
}

// ---------------------------------------------------------------------------
// K0: exact kNN via 2-level radix select (bit-identical distance math) + BN1.
__launch_bounds__(256)
__global__ void knn_kernel(const float* __restrict__ pos,
                           const float* __restrict__ w1, const float* __restrict__ b1,
                           float* __restrict__ out,
                           float* __restrict__ gp,
                           float* __restrict__ bn1sumr, float* __restrict__ bn1sqr) {
    __shared__ float px[NPTS], py[NPTS], pz[NPTS];
    __shared__ unsigned int dbits[NPTS];
    __shared__ unsigned int hist[HBINS];
    __shared__ unsigned int seg[256];
    __shared__ unsigned long long cand[256];
    __shared__ float gsx[KNN], gsy[KNN], gsz[KNN];
    __shared__ float red[256];
    __shared__ unsigned int s_b1, s_c0, s_p22, s_cnt;

    int t = threadIdx.x;
    int blk = blockIdx.x;
    int b = blk >> 11, n = blk & (NPTS - 1);
    const float* pb = pos + (size_t)b * NPTS * 3;
    for (int i = t; i < NPTS; i += 256) {
        px[i] = pb[i * 3 + 0]; py[i] = pb[i * 3 + 1]; pz[i] = pb[i * 3 + 2];
    }
    for (int i = t; i < HBINS; i += 256) hist[i] = 0;
    if (t == 0) s_cnt = 0;
    __syncthreads();

    float qx = px[n], qy = py[n], qz = pz[n];
    {
        #pragma clang fp contract(off)
        float sqi = (qx * qx + qy * qy) + qz * qz;
        for (int j = t; j < NPTS; j += 256) {
            float xj = px[j], yj = py[j], zj = pz[j];
            float sqj = (xj * xj + yj * yj) + zj * zj;
            float dot = fmaf(qz, zj, fmaf(qy, yj, qx * xj));
            float d2 = (sqi + sqj) - 2.0f * dot;
            float dist = sqrtf(fmaxf(d2, 0.0f));
            unsigned int bits = __float_as_uint(dist);
            dbits[j] = bits;
            atomicAdd(&hist[bits >> 20], 1u);
        }
    }
    __syncthreads();
    {
        unsigned int s = 0;
        #pragma unroll
        for (int q = 0; q < 8; ++q) s += hist[t * 8 + q];
        seg[t] = s;
        __syncthreads();
        for (int off = 1; off < 256; off <<= 1) {
            unsigned int v = seg[t];
            unsigned int u = (t >= off) ? seg[t - off] : 0;
            __syncthreads();
            seg[t] = v + u;
            __syncthreads();
        }
        unsigned int before = (t == 0) ? 0u : seg[t - 1];
        unsigned int incl = seg[t];
        if (before <= 127u && 127u < incl) {
            unsigned int c = before;
            for (int q = 0; q < 8; ++q) {
                unsigned int h = hist[t * 8 + q];
                if (c + h > 127u) { s_b1 = t * 8 + q; s_c0 = c; break; }
                c += h;
            }
        }
    }
    __syncthreads();
    unsigned int B1 = s_b1, c0 = s_c0;
    for (int i = t; i < HBINS; i += 256) hist[i] = 0;
    __syncthreads();
    for (int j = t; j < NPTS; j += 256) {
        unsigned int bits = dbits[j];
        if ((bits >> 20) == B1) atomicAdd(&hist[(bits >> 9) & 0x7FFu], 1u);
    }
    __syncthreads();
    {
        unsigned int target = 127u - c0;
        unsigned int s = 0;
        #pragma unroll
        for (int q = 0; q < 8; ++q) s += hist[t * 8 + q];
        seg[t] = s;
        __syncthreads();
        for (int off = 1; off < 256; off <<= 1) {
            unsigned int v = seg[t];
            unsigned int u = (t >= off) ? seg[t - off] : 0;
            __syncthreads();
            seg[t] = v + u;
            __syncthreads();
        }
        unsigned int before = (t == 0) ? 0u : seg[t - 1];
        unsigned int incl = seg[t];
        if (before <= target && target < incl) {
            unsigned int c = before;
            for (int q = 0; q < 8; ++q) {
                unsigned int h = hist[t * 8 + q];
                if (c + h > target) { s_p22 = (B1 << 11) | (unsigned)(t * 8 + q); break; }
                c += h;
            }
        }
    }
    cand[t] = 0xFFFFFFFFFFFFFFFFull;
    __syncthreads();
    unsigned int P22 = s_p22;
    for (int j = t; j < NPTS; j += 256) {
        unsigned int bits = dbits[j];
        if ((bits >> 9) <= P22) {
            unsigned int pos_ = atomicAdd(&s_cnt, 1u);
            if (pos_ < 256u) cand[pos_] = ((unsigned long long)bits << 32) | (unsigned int)j;
        }
    }
    __syncthreads();
    for (int k2 = 2; k2 <= 256; k2 <<= 1) {
        for (int s2 = k2 >> 1; s2 > 0; s2 >>= 1) {
            int l = t ^ s2;
            if (l > t) {
                unsigned long long a = cand[t], c = cand[l];
                bool up = ((t & k2) == 0);
                if ((a > c) == up) { cand[t] = c; cand[l] = a; }
            }
            __syncthreads();
        }
    }
    if (t < KNN) {
        unsigned int j = (unsigned int)(cand[t] & 0xffffffffu);
        out[FEAT_ELEMS + (size_t)blk * KNN + t] = (float)j;
        float gx_ = px[j] - qx, gy_ = py[j] - qy, gz_ = pz[j] - qz;
        gsx[t] = gx_; gsy[t] = gy_; gsz[t] = gz_;
        float* g = gp + ((size_t)blk * KNN + t) * 3;
        g[0] = gx_; g[1] = gy_; g[2] = gz_;
    }
    __syncthreads();
    int c = t & (C1 - 1);
    int half = t >> 7;
    float wa = w1[c * 3 + 0], wb = w1[c * 3 + 1], wc = w1[c * 3 + 2], bc = b1[c];
    float s = 0.f, q = 0.f;
    for (int r = half * 64; r < half * 64 + 64; ++r) {
        float f = wa * gsx[r] + wb * gsy[r] + wc * gsz[r] + bc;
        s += f; q += f * f;
    }
    red[t] = s; __syncthreads();
    int rep = blk & (NREP - 1);
    if (t < C1) atomicAdd(bn1sumr + rep * C1 + t, red[t] + red[t + C1]);
    __syncthreads();
    red[t] = q; __syncthreads();
    if (t < C1) atomicAdd(bn1sqr + rep * C1 + t, red[t] + red[t + C1]);
}

// ---------------------------------------------------------------------------
__global__ void bn_finalize(const float* __restrict__ sumr, const float* __restrict__ sqr,
                            const float* __restrict__ g, const float* __restrict__ be,
                            float* __restrict__ scale, float* __restrict__ shift,
                            int nch, float inv_count) {
    int c = blockIdx.x * blockDim.x + threadIdx.x;
    if (c < nch) {
        float s = 0.f, q = 0.f;
        for (int r = 0; r < NREP; ++r) { s += sumr[r * nch + c]; q += sqr[r * nch + c]; }
        float m = s * inv_count;
        float v = fmaxf(q * inv_count - m * m, 0.f);
        float sc = g[c] / sqrtf(v + 1e-5f);
        scale[c] = sc;
        shift[c] = be[c] - m * sc;
    }
}

// ---------------------------------------------------------------------------
__launch_bounds__(256)
__global__ void stats2_kernel(const float* __restrict__ gp,
                              const float* __restrict__ w1, const float* __restrict__ b1,
                              const float* __restrict__ sc1, const float* __restrict__ sh1,
                              const float* __restrict__ w2t, const float* __restrict__ b2,
                              const float* __restrict__ w3t, const float* __restrict__ b3,
                              float* __restrict__ fgout,
                              float* __restrict__ bn2sumr, float* __restrict__ bn2sqr) {
    __shared__ float gfl[KNN * 3];
    __shared__ float w1s[C1 * 3], b1s[C1], sc1s[C1], sh1s[C1];
    __shared__ float h1[C1][PAD];
    __shared__ float f2s[C2][PAD];
    __shared__ float fgs[C2];
    int t = threadIdx.x, blk = blockIdx.x;
    const float* g = gp + (size_t)blk * KNN * 3;
    for (int i = t; i < KNN * 3; i += 256) gfl[i] = g[i];
    for (int i = t; i < C1 * 3; i += 256) w1s[i] = w1[i];
    if (t < C1) { b1s[t] = b1[t]; sc1s[t] = sc1[t]; sh1s[t] = sh1[t]; }
    fgs[t] = -3.4e38f;
    __syncthreads();

    float m1 = 0.f, m2 = 0.f, q1 = 0.f, q2 = 0.f;
    for (int ch = 0; ch < NCHUNK; ++ch) {
        int j0 = ch * JC;
        for (int e = t; e < C1 * JC; e += 256) {
            int cc = e >> 4, j = e & (JC - 1);
            int jj = j0 + j;
            float f = w1s[cc*3] * gfl[jj*3] + w1s[cc*3+1] * gfl[jj*3+1] + w1s[cc*3+2] * gfl[jj*3+2] + b1s[cc];
            h1[cc][j] = fmaxf(f * sc1s[cc] + sh1s[cc], 0.f);
        }
        __syncthreads();
        float acc[JC];
        #pragma unroll
        for (int j = 0; j < JC; ++j) acc[j] = 0.f;
        for (int c1_ = 0; c1_ < C1; ++c1_) {
            float w = w2t[c1_ * C2 + t];
            const float4* hr = (const float4*)h1[c1_];
            float4 h0 = hr[0], h1v = hr[1], h2 = hr[2], h3 = hr[3];
            acc[0] += w*h0.x;  acc[1] += w*h0.y;  acc[2] += w*h0.z;  acc[3] += w*h0.w;
            acc[4] += w*h1v.x; acc[5] += w*h1v.y; acc[6] += w*h1v.z; acc[7] += w*h1v.w;
            acc[8] += w*h2.x;  acc[9] += w*h2.y;  acc[10]+= w*h2.z;  acc[11]+= w*h2.w;
            acc[12]+= w*h3.x;  acc[13]+= w*h3.y;  acc[14]+= w*h3.z;  acc[15]+= w*h3.w;
        }
        float bb = b2[t];
        float mx = -3.4e38f;
        float4* fw = (float4*)f2s[t];
        #pragma unroll
        for (int qd = 0; qd < 4; ++qd) {
            float v0 = acc[qd*4+0] + bb, v1 = acc[qd*4+1] + bb, v2 = acc[qd*4+2] + bb, v3 = acc[qd*4+3] + bb;
            fw[qd] = make_float4(v0, v1, v2, v3);
            mx = fmaxf(mx, fmaxf(fmaxf(v0, v1), fmaxf(v2, v3)));
        }
        fgs[t] = fmaxf(fgs[t], mx);
        __syncthreads();
        float a0[JC], a1[JC];
        #pragma unroll
        for (int j = 0; j < JC; ++j) { a0[j] = 0.f; a1[j] = 0.f; }
        for (int c2_ = 0; c2_ < C2; ++c2_) {
            const float* wr = w3t + (size_t)(C2 + c2_) * C3;
            float wA = wr[t], wB = wr[t + 256];
            const float4* fr = (const float4*)f2s[c2_];
            float4 f0 = fr[0], f1 = fr[1], f2 = fr[2], f3 = fr[3];
            a0[0] += wA*f0.x;  a0[1] += wA*f0.y;  a0[2] += wA*f0.z;  a0[3] += wA*f0.w;
            a0[4] += wA*f1.x;  a0[5] += wA*f1.y;  a0[6] += wA*f1.z;  a0[7] += wA*f1.w;
            a0[8] += wA*f2.x;  a0[9] += wA*f2.y;  a0[10]+= wA*f2.z;  a0[11]+= wA*f2.w;
            a0[12]+= wA*f3.x;  a0[13]+= wA*f3.y;  a0[14]+= wA*f3.z;  a0[15]+= wA*f3.w;
            a1[0] += wB*f0.x;  a1[1] += wB*f0.y;  a1[2] += wB*f0.z;  a1[3] += wB*f0.w;
            a1[4] += wB*f1.x;  a1[5] += wB*f1.y;  a1[6] += wB*f1.z;  a1[7] += wB*f1.w;
            a1[8] += wB*f2.x;  a1[9] += wB*f2.y;  a1[10]+= wB*f2.z;  a1[11]+= wB*f2.w;
            a1[12]+= wB*f3.x;  a1[13]+= wB*f3.y;  a1[14]+= wB*f3.z;  a1[15]+= wB*f3.w;
        }
        #pragma unroll
        for (int j = 0; j < JC; ++j) {
            m1 += a0[j]; q1 += a0[j] * a0[j];
            m2 += a1[j]; q2 += a1[j] * a1[j];
        }
        __syncthreads();
    }
    float c3a = b3[t], c3b = b3[t + 256];
    for (int c2_ = 0; c2_ < C2; ++c2_) {
        float f = fgs[c2_];
        c3a += w3t[(size_t)c2_ * C3 + t] * f;
        c3b += w3t[(size_t)c2_ * C3 + t + 256] * f;
    }
    int rep = blk & (NREP - 1);
    atomicAdd(bn2sumr + rep * C3 + t,        m1 + 128.f * c3a);
    atomicAdd(bn2sqr  + rep * C3 + t,        q1 + 2.f * c3a * m1 + 128.f * c3a * c3a);
    atomicAdd(bn2sumr + rep * C3 + t + 256,  m2 + 128.f * c3b);
    atomicAdd(bn2sqr  + rep * C3 + t + 256,  q2 + 2.f * c3b * m2 + 128.f * c3b * c3b);
    fgout[(size_t)blk * C2 + t] = fgs[t];
}

// ---------------------------------------------------------------------------
// K3 (MFMA): conv2/conv3/conv4 as 16x16x32 bf16 MFMA, hi/lo split, 3 products.
// Activations staged per 16-neighbor chunk in LDS [n][k] (k contiguous, +8 pad).
// A-operand (weights) streamed from global bf16 planes; fg-half of conv3 is the
// analytic c3s vector (fp32), added in the conv3 epilogue before BN2+ReLU.
__launch_bounds__(256)
__global__ void final_mfma_kernel(const float* __restrict__ gp,
                                  const float* __restrict__ w1, const float* __restrict__ b1,
                                  const float* __restrict__ sc1, const float* __restrict__ sh1,
                                  const unsigned short* __restrict__ w2hg, const unsigned short* __restrict__ w2lg,
                                  const float* __restrict__ b2,
                                  const float* __restrict__ w3t,
                                  const unsigned short* __restrict__ w3bh, const unsigned short* __restrict__ w3bl,
                                  const float* __restrict__ b3,
                                  const float* __restrict__ sc2, const float* __restrict__ sh2,
                                  const unsigned short* __restrict__ w4hg, const unsigned short* __restrict__ w4lg,
                                  const float* __restrict__ b4,
                                  const float* __restrict__ fgin, float* __restrict__ out) {
    __shared__ float gfl[KNN * 3];
    __shared__ float w1s[C1 * 3], b1s[C1], sc1s[C1], sh1s[C1];
    __shared__ float fgs[C2];
    __shared__ float c3s[C3], sc2s[C3], sh2s[C3];
    __shared__ unsigned short h1h[16][136], h1l[16][136];   // [n][k=c1], pad 8
    __shared__ unsigned short f2h[16][264], f2l[16][264];   // [n][k=c2]
    __shared__ unsigned short g3h[16][520], g3l[16][520];   // [n][k=c3]
    __shared__ float fmaxbuf[C4];

    int t = threadIdx.x, blk = blockIdx.x;
    int lane = t & 63, wave = t >> 6;
    int lrow = lane & 15, lq = lane >> 4;

    const float* g = gp + (size_t)blk * KNN * 3;
    for (int i = t; i < KNN * 3; i += 256) gfl[i] = g[i];
    for (int i = t; i < C1 * 3; i += 256) w1s[i] = w1[i];
    if (t < C1) { b1s[t] = b1[t]; sc1s[t] = sc1[t]; sh1s[t] = sh1[t]; }
    fgs[t] = fgin[(size_t)blk * C2 + t];
    for (int i = t; i < C3; i += 256) { sc2s[i] = sc2[i]; sh2s[i] = sh2[i]; }
    __syncthreads();
    {   // c3s = b3 + W3a * fg (fg-broadcast half of conv3), fp32
        float c3a = b3[t], c3b = b3[t + 256];
        for (int c2_ = 0; c2_ < C2; ++c2_) {
            float f = fgs[c2_];
            c3a += w3t[(size_t)c2_ * C3 + t] * f;
            c3b += w3t[(size_t)c2_ * C3 + t + 256] * f;
        }
        c3s[t] = c3a; c3s[t + 256] = c3b;
    }
    __syncthreads();

    const float4v zero4 = {0.f, 0.f, 0.f, 0.f};
    float rm[2][4];
    #pragma unroll
    for (int i = 0; i < 2; ++i)
        #pragma unroll
        for (int r = 0; r < 4; ++r) rm[i][r] = -3.4e38f;

    for (int ch = 0; ch < 8; ++ch) {
        // ---- conv1 + BN1 + ReLU -> h1 (bf16 hi/lo) ----
        {
            int n = t >> 4;
            int c1b = (t & 15) * 8;
            int j = ch * 16 + n;
            float gx = gfl[j * 3], gy = gfl[j * 3 + 1], gz = gfl[j * 3 + 2];
            short8 vh, vl;
            #pragma unroll
            for (int e = 0; e < 8; ++e) {
                int c = c1b + e;
                float f = w1s[c*3] * gx + w1s[c*3+1] * gy + w1s[c*3+2] * gz + b1s[c];
                float v = fmaxf(f * sc1s[c] + sh1s[c], 0.f);
                unsigned short h = f2bf(v);
                vh[e] = (short)h;
                vl[e] = (short)f2bf(v - bf2f(h));
            }
            *(short8*)&h1h[n][c1b] = vh;
            *(short8*)&h1l[n][c1b] = vl;
        }
        __syncthreads();

        // ---- conv2: M=256 (4 mtiles/wave), K=128, N=16 ----
        {
            float4v acc[4];
            #pragma unroll
            for (int i = 0; i < 4; ++i) acc[i] = zero4;
            for (int ks = 0; ks < 4; ++ks) {
                int ko = ks * 32 + lq * 8;
                short8 bh = *(const short8*)&h1h[lrow][ko];
                short8 bl = *(const short8*)&h1l[lrow][ko];
                #pragma unroll
                for (int i = 0; i < 4; ++i) {
                    int m = (wave * 4 + i) * 16 + lrow;
                    short8 ah = *(const short8*)&w2hg[m * C1 + ko];
                    short8 al = *(const short8*)&w2lg[m * C1 + ko];
                    acc[i] = MFMA16(ah, bh, acc[i]);
                    acc[i] = MFMA16(ah, bl, acc[i]);
                    acc[i] = MFMA16(al, bh, acc[i]);
                }
            }
            #pragma unroll
            for (int i = 0; i < 4; ++i) {
                int mbase = (wave * 4 + i) * 16 + lq * 4;
                #pragma unroll
                for (int r = 0; r < 4; ++r) {
                    float v = acc[i][r] + b2[mbase + r];
                    unsigned short h = f2bf(v);
                    f2h[lrow][mbase + r] = h;
                    f2l[lrow][mbase + r] = f2bf(v - bf2f(h));
                }
            }
        }
        __syncthreads();

        // ---- conv3 (f2 half): M=512 (8 mtiles/wave), K=256, N=16; +c3s, BN2, ReLU ----
        {
            float4v acc[8];
            #pragma unroll
            for (int i = 0; i < 8; ++i) acc[i] = zero4;
            for (int ks = 0; ks < 8; ++ks) {
                int ko = ks * 32 + lq * 8;
                short8 bh = *(const short8*)&f2h[lrow][ko];
                short8 bl = *(const short8*)&f2l[lrow][ko];
                #pragma unroll
                for (int i = 0; i < 8; ++i) {
                    int m = (wave * 8 + i) * 16 + lrow;
                    short8 ah = *(const short8*)&w3bh[m * C2 + ko];
                    short8 al = *(const short8*)&w3bl[m * C2 + ko];
                    acc[i] = MFMA16(ah, bh, acc[i]);
                    acc[i] = MFMA16(ah, bl, acc[i]);
                    acc[i] = MFMA16(al, bh, acc[i]);
                }
            }
            #pragma unroll
            for (int i = 0; i < 8; ++i) {
                int mbase = (wave * 8 + i) * 16 + lq * 4;
                #pragma unroll
                for (int r = 0; r < 4; ++r) {
                    int m = mbase + r;
                    float f3 = acc[i][r] + c3s[m];
                    float v = fmaxf(f3 * sc2s[m] + sh2s[m], 0.f);
                    unsigned short h = f2bf(v);
                    g3h[lrow][m] = h;
                    g3l[lrow][m] = f2bf(v - bf2f(h));
                }
            }
        }
        __syncthreads();

        // ---- conv4: M=128 (2 mtiles/wave), K=512, N=16; running max ----
        {
            float4v acc[2];
            acc[0] = zero4; acc[1] = zero4;
            for (int ks = 0; ks < 16; ++ks) {
                int ko = ks * 32 + lq * 8;
                short8 bh = *(const short8*)&g3h[lrow][ko];
                short8 bl = *(const short8*)&g3l[lrow][ko];
                #pragma unroll
                for (int i = 0; i < 2; ++i) {
                    int m = (wave * 2 + i) * 16 + lrow;
                    short8 ah = *(const short8*)&w4hg[m * C3 + ko];
                    short8 al = *(const short8*)&w4lg[m * C3 + ko];
                    acc[i] = MFMA16(ah, bh, acc[i]);
                    acc[i] = MFMA16(ah, bl, acc[i]);
                    acc[i] = MFMA16(al, bh, acc[i]);
                }
            }
            #pragma unroll
            for (int i = 0; i < 2; ++i)
                #pragma unroll
                for (int r = 0; r < 4; ++r) rm[i][r] = fmaxf(rm[i][r], acc[i][r]);
        }
        // no barrier needed: next conv1 writes h1 (consumed before prior B2),
        // g3 is rewritten only after the next conv3 barrier.
    }

    // ---- reduce max over the 16 columns (lanes with same quad) ----
    #pragma unroll
    for (int i = 0; i < 2; ++i) {
        #pragma unroll
        for (int r = 0; r < 4; ++r) {
            float v = rm[i][r];
            v = fmaxf(v, __shfl_xor(v, 1));
            v = fmaxf(v, __shfl_xor(v, 2));
            v = fmaxf(v, __shfl_xor(v, 4));
            v = fmaxf(v, __shfl_xor(v, 8));
            if ((lane & 15) == 0) fmaxbuf[(wave * 2 + i) * 16 + lq * 4 + r] = v;
        }
    }
    __syncthreads();
    if (t < C4) {
        float v = fmaxbuf[t] + b4[t];
        int b = blk >> 11, n = blk & (NPTS - 1);
        out[((size_t)b * C4 + t) * NPTS + n] = v;
    }
}

// ---------------------------------------------------------------------------
extern "C" void kernel_launch(void* const* d_in, const int* in_sizes, int n_in,
                              void* d_out, int out_size, void* d_ws, size_t ws_size,
                              hipStream_t stream) {
    const float* pos = (const float*)d_in[0];
    const float* w1  = (const float*)d_in[1];
    const float* b1  = (const float*)d_in[2];
    const float* g1  = (const float*)d_in[3];
    const float* be1 = (const float*)d_in[4];
    const float* w2  = (const float*)d_in[5];
    const float* b2  = (const float*)d_in[6];
    const float* w3  = (const float*)d_in[7];
    const float* b3  = (const float*)d_in[8];
    const float* g2  = (const float*)d_in[9];
    const float* be2 = (const float*)d_in[10];
    const float* w4  = (const float*)d_in[11];
    const float* b4  = (const float*)d_in[12];
    float* out = (float*)d_out;
    float* ws  = (float*)d_ws;

    float* gp      = ws;                          // 1572864
    float* w2t     = gp + 1572864;                // 32768
    float* w3t     = w2t + 32768;                 // 262144
    float* bn1sumr = w3t + 262144;                // 1024
    float* bn1sqr  = bn1sumr + NREP * C1;         // 1024
    float* bn2sumr = bn1sqr + NREP * C1;          // 4096
    float* bn2sqr  = bn2sumr + NREP * C3;         // 4096
    float* sc1     = bn2sqr + NREP * C3;          // 128
    float* sh1     = sc1 + 128;                   // 128
    float* sc2     = sh1 + 128;                   // 512
    float* sh2     = sc2 + 512;                   // 512
    float* fg      = sh2 + 512;                   // 1048576
    unsigned short* uw = (unsigned short*)(fg + 1048576);
    unsigned short* w2hg = uw;                    // 32768
    unsigned short* w2lg = uw + 32768;            // 32768
    unsigned short* w3bh = uw + 65536;            // 131072
    unsigned short* w3bl = uw + 196608;           // 131072
    unsigned short* w4hg = uw + 327680;           // 65536
    unsigned short* w4lg = uw + 393216;           // 65536  (end: 458752 halves)

    hipMemsetAsync(bn1sumr, 0, (size_t)(2 * NREP * C1 + 2 * NREP * C3) * sizeof(float), stream);
    prep_kernel<<<512, 256, 0, stream>>>(w2, w3, w4, w2t, w3t,
                                         w2hg, w2lg, w3bh, w3bl, w4hg, w4lg);
    knn_kernel<<<NGROUP, 256, 0, stream>>>(pos, w1, b1, out, gp, bn1sumr, bn1sqr);
    bn_finalize<<<1, 128, 0, stream>>>(bn1sumr, bn1sqr, g1, be1, sc1, sh1, C1, 1.f / 524288.f);
    stats2_kernel<<<NGROUP, 256, 0, stream>>>(gp, w1, b1, sc1, sh1, w2t, b2, w3t, b3,
                                              fg, bn2sumr, bn2sqr);
    bn_finalize<<<1, 512, 0, stream>>>(bn2sumr, bn2sqr, g2, be2, sc2, sh2, C3, 1.f / 524288.f);
    final_mfma_kernel<<<NGROUP, 256, 0, stream>>>(gp, w1, b1, sc1, sh1,
                                                  w2hg, w2lg, b2, w3t, w3bh, w3bl, b3,
                                                  sc2, sh2, w4hg, w4lg, b4, fg, out);
}

// Round 5
// 3121.850 us; speedup vs baseline: 2.8896x; 2.8896x over previous
//
#include <hip/hip_runtime.h>
#include <stdint.h>

#define NPTS  2048
#define BATCH 2
#define KNN   128
#define C1    128
#define C2    256
#define C3    512
#define C4    128
#define JC    16
#define PAD   20
#define NCHUNK (KNN / JC)        // 8
#define NGROUP (BATCH * NPTS)    // 4096
#define FEAT_ELEMS (BATCH * C4 * NPTS)  // 524288
#define HBINS 2048
#define NREP  8

typedef short short8 __attribute__((ext_vector_type(8)));
typedef short short4v __attribute__((ext_vector_type(4)));
typedef float float4v __attribute__((ext_vector_type(4)));
#define MFMA16(a, b, c) __builtin_amdgcn_mfma_f32_16x16x32_bf16(a, b, c, 0, 0, 0)

__device__ __host__ inline unsigned short f2bf(float x) {
    unsigned u = __float_as_uint(x);
    return (unsigned short)((u + 0x7fffu + ((u >> 16) & 1u)) >> 16);
}
__device__ inline float bf2f(unsigned short s) {
    return __uint_as_float(((unsigned)s) << 16);
}

// ---------------------------------------------------------------------------
__global__ void prep_kernel(const float* __restrict__ w2, const float* __restrict__ w3,
                            const float* __restrict__ w4,
                            float* __restrict__ w2t, float* __restrict__ w3t,
                            unsigned short* __restrict__ w2hg, unsigned short* __restrict__ w2lg,
                            unsigned short* __restrict__ w3bh, unsigned short* __restrict__ w3bl,
                            unsigned short* __restrict__ w4hg, unsigned short* __restrict__ w4lg) {
    int tid = blockIdx.x * blockDim.x + threadIdx.x;
    int stride = gridDim.x * blockDim.x;
    for (int i = tid; i < C2 * C1; i += stride) {
        float v = w2[i];
        w2t[(i & (C1 - 1)) * C2 + (i >> 7)] = v;
        unsigned short h = f2bf(v);
        w2hg[i] = h; w2lg[i] = f2bf(v - bf2f(h));
    }
    for (int i = tid; i < C3 * C3; i += stride) w3t[(i & (C3 - 1)) * C3 + (i >> 9)] = w3[i];
    for (int i = tid; i < C3 * C2; i += stride) {
        int m = i >> 8, k = i & 255;
        float v = w3[m * C3 + C2 + k];
        unsigned short h = f2bf(v);
        w3bh[i] = h; w3bl[i] = f2bf(v - bf2f(h));
    }
    for (int i = tid; i < C4 * C3; i += stride) {
        float v = w4[i];
        unsigned short h = f2bf(v);
        w4hg[i] = h; w4lg[i] = f2bf(v - bf2f(h));
    }
}

// ---------------------------------------------------------------------------
// K0: exact kNN via 2-level radix select (bit-identical distance math) + BN1.
__launch_bounds__(256)
__global__ void knn_kernel(const float* __restrict__ pos,
                           const float* __restrict__ w1, const float* __restrict__ b1,
                           float* __restrict__ out,
                           float* __restrict__ gp,
                           float* __restrict__ bn1sumr, float* __restrict__ bn1sqr) {
    __shared__ float px[NPTS], py[NPTS], pz[NPTS];
    __shared__ unsigned int dbits[NPTS];
    __shared__ unsigned int hist[HBINS];
    __shared__ unsigned int seg[256];
    __shared__ unsigned long long cand[256];
    __shared__ float gsx[KNN], gsy[KNN], gsz[KNN];
    __shared__ float red[256];
    __shared__ unsigned int s_b1, s_c0, s_p22, s_cnt;

    int t = threadIdx.x;
    int blk = blockIdx.x;
    int b = blk >> 11, n = blk & (NPTS - 1);
    const float* pb = pos + (size_t)b * NPTS * 3;
    for (int i = t; i < NPTS; i += 256) {
        px[i] = pb[i * 3 + 0]; py[i] = pb[i * 3 + 1]; pz[i] = pb[i * 3 + 2];
    }
    for (int i = t; i < HBINS; i += 256) hist[i] = 0;
    if (t == 0) s_cnt = 0;
    __syncthreads();

    float qx = px[n], qy = py[n], qz = pz[n];
    {
        #pragma clang fp contract(off)
        float sqi = (qx * qx + qy * qy) + qz * qz;
        for (int j = t; j < NPTS; j += 256) {
            float xj = px[j], yj = py[j], zj = pz[j];
            float sqj = (xj * xj + yj * yj) + zj * zj;
            float dot = fmaf(qz, zj, fmaf(qy, yj, qx * xj));
            float d2 = (sqi + sqj) - 2.0f * dot;
            float dist = sqrtf(fmaxf(d2, 0.0f));
            unsigned int bits = __float_as_uint(dist);
            dbits[j] = bits;
            atomicAdd(&hist[bits >> 20], 1u);
        }
    }
    __syncthreads();
    {
        unsigned int s = 0;
        #pragma unroll
        for (int q = 0; q < 8; ++q) s += hist[t * 8 + q];
        seg[t] = s;
        __syncthreads();
        for (int off = 1; off < 256; off <<= 1) {
            unsigned int v = seg[t];
            unsigned int u = (t >= off) ? seg[t - off] : 0;
            __syncthreads();
            seg[t] = v + u;
            __syncthreads();
        }
        unsigned int before = (t == 0) ? 0u : seg[t - 1];
        unsigned int incl = seg[t];
        if (before <= 127u && 127u < incl) {
            unsigned int c = before;
            for (int q = 0; q < 8; ++q) {
                unsigned int h = hist[t * 8 + q];
                if (c + h > 127u) { s_b1 = t * 8 + q; s_c0 = c; break; }
                c += h;
            }
        }
    }
    __syncthreads();
    unsigned int B1 = s_b1, c0 = s_c0;
    for (int i = t; i < HBINS; i += 256) hist[i] = 0;
    __syncthreads();
    for (int j = t; j < NPTS; j += 256) {
        unsigned int bits = dbits[j];
        if ((bits >> 20) == B1) atomicAdd(&hist[(bits >> 9) & 0x7FFu], 1u);
    }
    __syncthreads();
    {
        unsigned int target = 127u - c0;
        unsigned int s = 0;
        #pragma unroll
        for (int q = 0; q < 8; ++q) s += hist[t * 8 + q];
        seg[t] = s;
        __syncthreads();
        for (int off = 1; off < 256; off <<= 1) {
            unsigned int v = seg[t];
            unsigned int u = (t >= off) ? seg[t - off] : 0;
            __syncthreads();
            seg[t] = v + u;
            __syncthreads();
        }
        unsigned int before = (t == 0) ? 0u : seg[t - 1];
        unsigned int incl = seg[t];
        if (before <= target && target < incl) {
            unsigned int c = before;
            for (int q = 0; q < 8; ++q) {
                unsigned int h = hist[t * 8 + q];
                if (c + h > target) { s_p22 = (B1 << 11) | (unsigned)(t * 8 + q); break; }
                c += h;
            }
        }
    }
    cand[t] = 0xFFFFFFFFFFFFFFFFull;
    __syncthreads();
    unsigned int P22 = s_p22;
    for (int j = t; j < NPTS; j += 256) {
        unsigned int bits = dbits[j];
        if ((bits >> 9) <= P22) {
            unsigned int pos_ = atomicAdd(&s_cnt, 1u);
            if (pos_ < 256u) cand[pos_] = ((unsigned long long)bits << 32) | (unsigned int)j;
        }
    }
    __syncthreads();
    for (int k2 = 2; k2 <= 256; k2 <<= 1) {
        for (int s2 = k2 >> 1; s2 > 0; s2 >>= 1) {
            int l = t ^ s2;
            if (l > t) {
                unsigned long long a = cand[t], c = cand[l];
                bool up = ((t & k2) == 0);
                if ((a > c) == up) { cand[t] = c; cand[l] = a; }
            }
            __syncthreads();
        }
    }
    if (t < KNN) {
        unsigned int j = (unsigned int)(cand[t] & 0xffffffffu);
        out[FEAT_ELEMS + (size_t)blk * KNN + t] = (float)j;
        float gx_ = px[j] - qx, gy_ = py[j] - qy, gz_ = pz[j] - qz;
        gsx[t] = gx_; gsy[t] = gy_; gsz[t] = gz_;
        float* g = gp + ((size_t)blk * KNN + t) * 3;
        g[0] = gx_; g[1] = gy_; g[2] = gz_;
    }
    __syncthreads();
    int c = t & (C1 - 1);
    int half = t >> 7;
    float wa = w1[c * 3 + 0], wb = w1[c * 3 + 1], wc = w1[c * 3 + 2], bc = b1[c];
    float s = 0.f, q = 0.f;
    for (int r = half * 64; r < half * 64 + 64; ++r) {
        float f = wa * gsx[r] + wb * gsy[r] + wc * gsz[r] + bc;
        s += f; q += f * f;
    }
    red[t] = s; __syncthreads();
    int rep = blk & (NREP - 1);
    if (t < C1) atomicAdd(bn1sumr + rep * C1 + t, red[t] + red[t + C1]);
    __syncthreads();
    red[t] = q; __syncthreads();
    if (t < C1) atomicAdd(bn1sqr + rep * C1 + t, red[t] + red[t + C1]);
}

// ---------------------------------------------------------------------------
__global__ void bn_finalize(const float* __restrict__ sumr, const float* __restrict__ sqr,
                            const float* __restrict__ g, const float* __restrict__ be,
                            float* __restrict__ scale, float* __restrict__ shift,
                            int nch, float inv_count) {
    int c = blockIdx.x * blockDim.x + threadIdx.x;
    if (c < nch) {
        float s = 0.f, q = 0.f;
        for (int r = 0; r < NREP; ++r) { s += sumr[r * nch + c]; q += sqr[r * nch + c]; }
        float m = s * inv_count;
        float v = fmaxf(q * inv_count - m * m, 0.f);
        float sc = g[c] / sqrtf(v + 1e-5f);
        scale[c] = sc;
        shift[c] = be[c] - m * sc;
    }
}

// ---------------------------------------------------------------------------
// stats2: BN2 moments + per-group c3 vector (b3 + W3a·fg) stored to c3buf.
__launch_bounds__(256)
__global__ void stats2_kernel(const float* __restrict__ gp,
                              const float* __restrict__ w1, const float* __restrict__ b1,
                              const float* __restrict__ sc1, const float* __restrict__ sh1,
                              const float* __restrict__ w2t, const float* __restrict__ b2,
                              const float* __restrict__ w3t, const float* __restrict__ b3,
                              float* __restrict__ c3buf,
                              float* __restrict__ bn2sumr, float* __restrict__ bn2sqr) {
    __shared__ float gfl[KNN * 3];
    __shared__ float w1s[C1 * 3], b1s[C1], sc1s[C1], sh1s[C1];
    __shared__ float h1[C1][PAD];
    __shared__ float f2s[C2][PAD];
    __shared__ float fgs[C2];
    int t = threadIdx.x, blk = blockIdx.x;
    const float* g = gp + (size_t)blk * KNN * 3;
    for (int i = t; i < KNN * 3; i += 256) gfl[i] = g[i];
    for (int i = t; i < C1 * 3; i += 256) w1s[i] = w1[i];
    if (t < C1) { b1s[t] = b1[t]; sc1s[t] = sc1[t]; sh1s[t] = sh1[t]; }
    fgs[t] = -3.4e38f;
    __syncthreads();

    float m1 = 0.f, m2 = 0.f, q1 = 0.f, q2 = 0.f;
    for (int ch = 0; ch < NCHUNK; ++ch) {
        int j0 = ch * JC;
        for (int e = t; e < C1 * JC; e += 256) {
            int cc = e >> 4, j = e & (JC - 1);
            int jj = j0 + j;
            float f = w1s[cc*3] * gfl[jj*3] + w1s[cc*3+1] * gfl[jj*3+1] + w1s[cc*3+2] * gfl[jj*3+2] + b1s[cc];
            h1[cc][j] = fmaxf(f * sc1s[cc] + sh1s[cc], 0.f);
        }
        __syncthreads();
        float acc[JC];
        #pragma unroll
        for (int j = 0; j < JC; ++j) acc[j] = 0.f;
        for (int c1_ = 0; c1_ < C1; ++c1_) {
            float w = w2t[c1_ * C2 + t];
            const float4* hr = (const float4*)h1[c1_];
            float4 h0 = hr[0], h1v = hr[1], h2 = hr[2], h3 = hr[3];
            acc[0] += w*h0.x;  acc[1] += w*h0.y;  acc[2] += w*h0.z;  acc[3] += w*h0.w;
            acc[4] += w*h1v.x; acc[5] += w*h1v.y; acc[6] += w*h1v.z; acc[7] += w*h1v.w;
            acc[8] += w*h2.x;  acc[9] += w*h2.y;  acc[10]+= w*h2.z;  acc[11]+= w*h2.w;
            acc[12]+= w*h3.x;  acc[13]+= w*h3.y;  acc[14]+= w*h3.z;  acc[15]+= w*h3.w;
        }
        float bb = b2[t];
        float mx = -3.4e38f;
        float4* fw = (float4*)f2s[t];
        #pragma unroll
        for (int qd = 0; qd < 4; ++qd) {
            float v0 = acc[qd*4+0] + bb, v1 = acc[qd*4+1] + bb, v2 = acc[qd*4+2] + bb, v3 = acc[qd*4+3] + bb;
            fw[qd] = make_float4(v0, v1, v2, v3);
            mx = fmaxf(mx, fmaxf(fmaxf(v0, v1), fmaxf(v2, v3)));
        }
        fgs[t] = fmaxf(fgs[t], mx);
        __syncthreads();
        float a0[JC], a1[JC];
        #pragma unroll
        for (int j = 0; j < JC; ++j) { a0[j] = 0.f; a1[j] = 0.f; }
        for (int c2_ = 0; c2_ < C2; ++c2_) {
            const float* wr = w3t + (size_t)(C2 + c2_) * C3;
            float wA = wr[t], wB = wr[t + 256];
            const float4* fr = (const float4*)f2s[c2_];
            float4 f0 = fr[0], f1 = fr[1], f2 = fr[2], f3 = fr[3];
            a0[0] += wA*f0.x;  a0[1] += wA*f0.y;  a0[2] += wA*f0.z;  a0[3] += wA*f0.w;
            a0[4] += wA*f1.x;  a0[5] += wA*f1.y;  a0[6] += wA*f1.z;  a0[7] += wA*f1.w;
            a0[8] += wA*f2.x;  a0[9] += wA*f2.y;  a0[10]+= wA*f2.z;  a0[11]+= wA*f2.w;
            a0[12]+= wA*f3.x;  a0[13]+= wA*f3.y;  a0[14]+= wA*f3.z;  a0[15]+= wA*f3.w;
            a1[0] += wB*f0.x;  a1[1] += wB*f0.y;  a1[2] += wB*f0.z;  a1[3] += wB*f0.w;
            a1[4] += wB*f1.x;  a1[5] += wB*f1.y;  a1[6] += wB*f1.z;  a1[7] += wB*f1.w;
            a1[8] += wB*f2.x;  a1[9] += wB*f2.y;  a1[10]+= wB*f2.z;  a1[11]+= wB*f2.w;
            a1[12]+= wB*f3.x;  a1[13]+= wB*f3.y;  a1[14]+= wB*f3.z;  a1[15]+= wB*f3.w;
        }
        #pragma unroll
        for (int j = 0; j < JC; ++j) {
            m1 += a0[j]; q1 += a0[j] * a0[j];
            m2 += a1[j]; q2 += a1[j] * a1[j];
        }
        __syncthreads();
    }
    float c3a = b3[t], c3b = b3[t + 256];
    for (int c2_ = 0; c2_ < C2; ++c2_) {
        float f = fgs[c2_];
        c3a += w3t[(size_t)c2_ * C3 + t] * f;
        c3b += w3t[(size_t)c2_ * C3 + t + 256] * f;
    }
    int rep = blk & (NREP - 1);
    atomicAdd(bn2sumr + rep * C3 + t,        m1 + 128.f * c3a);
    atomicAdd(bn2sqr  + rep * C3 + t,        q1 + 2.f * c3a * m1 + 128.f * c3a * c3a);
    atomicAdd(bn2sumr + rep * C3 + t + 256,  m2 + 128.f * c3b);
    atomicAdd(bn2sqr  + rep * C3 + t + 256,  q2 + 2.f * c3b * m2 + 128.f * c3b * c3b);
    c3buf[(size_t)blk * C3 + t] = c3a;
    c3buf[(size_t)blk * C3 + t + 256] = c3b;
}

// ---------------------------------------------------------------------------
// final (MFMA, N=128): whole group per block. Weights read exactly once/block.
// h1 hi/lo (overlaid with g3-slice hi/lo), f2 single-bf16. conv3+conv4 fused
// over 4 k-slices of 128 channels; conv4 acc persistent in registers.
#define H1S 136   // h1/g3 row stride (shorts): 128 + 8 (16B-aligned, conflict-free)
#define F2S 264   // f2 row stride

__launch_bounds__(256, 1)
__global__ void final_mfma_kernel(const float* __restrict__ gp,
                                  const float* __restrict__ w1, const float* __restrict__ b1,
                                  const float* __restrict__ sc1, const float* __restrict__ sh1,
                                  const unsigned short* __restrict__ w2hg, const unsigned short* __restrict__ w2lg,
                                  const float* __restrict__ b2,
                                  const unsigned short* __restrict__ w3bh, const unsigned short* __restrict__ w3bl,
                                  const float* __restrict__ sc2, const float* __restrict__ sh2,
                                  const unsigned short* __restrict__ w4hg, const unsigned short* __restrict__ w4lg,
                                  const float* __restrict__ b4,
                                  const float* __restrict__ c3buf, float* __restrict__ out) {
    __shared__ __align__(16) unsigned short ovl[2 * 128 * H1S];   // h1 hi/lo  <->  g3-slice hi/lo
    __shared__ __align__(16) unsigned short f2s[128 * F2S];       // f2 single bf16 [n][c2]
    __shared__ float gfl[KNN * 3];
    __shared__ float w1s[C1 * 3], b1s[C1], sc1s[C1], sh1s[C1], b2s[C2];
    __shared__ float c3s[C3], sc2s[C3], sh2s[C3];
    __shared__ float fmaxbuf[C4];

    unsigned short* aH = ovl;                  // plane 0
    unsigned short* aL = ovl + 128 * H1S;      // plane 1

    int t = threadIdx.x, blk = blockIdx.x;
    int lane = t & 63, wave = t >> 6;
    int lrow = lane & 15, lq = lane >> 4;

    const float* g = gp + (size_t)blk * KNN * 3;
    for (int i = t; i < KNN * 3; i += 256) gfl[i] = g[i];
    for (int i = t; i < C1 * 3; i += 256) w1s[i] = w1[i];
    if (t < C1) { b1s[t] = b1[t]; sc1s[t] = sc1[t]; sh1s[t] = sh1[t]; }
    b2s[t] = b2[t];
    for (int i = t; i < C3; i += 256) {
        c3s[i] = c3buf[(size_t)blk * C3 + i];
        sc2s[i] = sc2[i]; sh2s[i] = sh2[i];
    }
    __syncthreads();

    // ---- conv1 + BN1 + ReLU -> h1 hi/lo (all 128 neighbors) ----
    {
        int n = t >> 1;
        int cb = (t & 1) * 64;
        float gx = gfl[n * 3], gy = gfl[n * 3 + 1], gz = gfl[n * 3 + 2];
        #pragma unroll
        for (int e8 = 0; e8 < 8; ++e8) {
            short8 vh, vl;
            #pragma unroll
            for (int e = 0; e < 8; ++e) {
                int c = cb + e8 * 8 + e;
                float f = w1s[c*3] * gx + w1s[c*3+1] * gy + w1s[c*3+2] * gz + b1s[c];
                float v = fmaxf(f * sc1s[c] + sh1s[c], 0.f);
                unsigned short h = f2bf(v);
                vh[e] = (short)h;
                vl[e] = (short)f2bf(v - bf2f(h));
            }
            *(short8*)&aH[n * H1S + cb + e8 * 8] = vh;
            *(short8*)&aL[n * H1S + cb + e8 * 8] = vl;
        }
    }
    __syncthreads();

    const float4v zero4 = {0.f, 0.f, 0.f, 0.f};

    // ---- conv2: M=256, K=128, N=128. Wave: 4 mtiles x 8 ntiles ----
    {
        float4v acc2[4][8];
        #pragma unroll
        for (int i = 0; i < 4; ++i)
            #pragma unroll
            for (int j = 0; j < 8; ++j) acc2[i][j] = zero4;
        for (int ks = 0; ks < 4; ++ks) {
            int ko = ks * 32 + lq * 8;
            short8 bh[8], bl[8];
            #pragma unroll
            for (int j = 0; j < 8; ++j) {
                bh[j] = *(const short8*)&aH[(j * 16 + lrow) * H1S + ko];
                bl[j] = *(const short8*)&aL[(j * 16 + lrow) * H1S + ko];
            }
            #pragma unroll
            for (int i = 0; i < 4; ++i) {
                int m = (wave * 4 + i) * 16 + lrow;
                short8 ah = *(const short8*)&w2hg[m * C1 + ko];
                short8 al = *(const short8*)&w2lg[m * C1 + ko];
                #pragma unroll
                for (int j = 0; j < 8; ++j) {
                    acc2[i][j] = MFMA16(ah, bh[j], acc2[i][j]);
                    acc2[i][j] = MFMA16(ah, bl[j], acc2[i][j]);
                    acc2[i][j] = MFMA16(al, bh[j], acc2[i][j]);
                }
            }
        }
        __syncthreads();   // all waves done reading h1 before f2 epilogue? (f2s separate; barrier protects nothing yet but orders h1 reuse later)
        // epilogue: bias + pack single bf16 -> f2s[n][m]
        #pragma unroll
        for (int i = 0; i < 4; ++i) {
            int mb = (wave * 4 + i) * 16 + lq * 4;
            float bb0 = b2s[mb], bb1 = b2s[mb+1], bb2 = b2s[mb+2], bb3 = b2s[mb+3];
            #pragma unroll
            for (int j = 0; j < 8; ++j) {
                int n = j * 16 + lrow;
                short4v p;
                p[0] = (short)f2bf(acc2[i][j][0] + bb0);
                p[1] = (short)f2bf(acc2[i][j][1] + bb1);
                p[2] = (short)f2bf(acc2[i][j][2] + bb2);
                p[3] = (short)f2bf(acc2[i][j][3] + bb3);
                *(short4v*)&f2s[n * F2S + mb] = p;
            }
        }
    }
    __syncthreads();

    // ---- conv3 + conv4 fused over 4 k-slices of 128 channels ----
    float4v acc4[2][8];
    #pragma unroll
    for (int i = 0; i < 2; ++i)
        #pragma unroll
        for (int j = 0; j < 8; ++j) acc4[i][j] = zero4;

    for (int s = 0; s < 4; ++s) {
        // conv3 slice: M=128 (wave: 2 mtiles x 8 ntiles), K=256
        float4v acc3[2][8];
        #pragma unroll
        for (int i = 0; i < 2; ++i)
            #pragma unroll
            for (int j = 0; j < 8; ++j) acc3[i][j] = zero4;
        for (int ks = 0; ks < 8; ++ks) {
            int ko = ks * 32 + lq * 8;
            short8 bh[8];
            #pragma unroll
            for (int j = 0; j < 8; ++j)
                bh[j] = *(const short8*)&f2s[(j * 16 + lrow) * F2S + ko];
            #pragma unroll
            for (int i = 0; i < 2; ++i) {
                int mg = s * 128 + (wave * 2 + i) * 16 + lrow;
                short8 ah = *(const short8*)&w3bh[mg * C2 + ko];
                short8 al = *(const short8*)&w3bl[mg * C2 + ko];
                #pragma unroll
                for (int j = 0; j < 8; ++j) {
                    acc3[i][j] = MFMA16(ah, bh[j], acc3[i][j]);
                    acc3[i][j] = MFMA16(al, bh[j], acc3[i][j]);
                }
            }
        }
        __syncthreads();   // previous conv4 done reading g3 overlay
        // epilogue: +c3, BN2, ReLU, pack hi/lo -> g3 slice (overlay)
        #pragma unroll
        for (int i = 0; i < 2; ++i) {
            int mbl = (wave * 2 + i) * 16 + lq * 4;       // local 0..127
            int mg  = s * 128 + mbl;
            float cA0 = c3s[mg],   sA0 = sc2s[mg],   hA0 = sh2s[mg];
            float cA1 = c3s[mg+1], sA1 = sc2s[mg+1], hA1 = sh2s[mg+1];
            float cA2 = c3s[mg+2], sA2 = sc2s[mg+2], hA2 = sh2s[mg+2];
            float cA3 = c3s[mg+3], sA3 = sc2s[mg+3], hA3 = sh2s[mg+3];
            #pragma unroll
            for (int j = 0; j < 8; ++j) {
                int n = j * 16 + lrow;
                float v0 = fmaxf((acc3[i][j][0] + cA0) * sA0 + hA0, 0.f);
                float v1 = fmaxf((acc3[i][j][1] + cA1) * sA1 + hA1, 0.f);
                float v2 = fmaxf((acc3[i][j][2] + cA2) * sA2 + hA2, 0.f);
                float v3 = fmaxf((acc3[i][j][3] + cA3) * sA3 + hA3, 0.f);
                short4v ph, pl;
                unsigned short h0 = f2bf(v0), h1 = f2bf(v1), h2 = f2bf(v2), h3 = f2bf(v3);
                ph[0]=(short)h0; ph[1]=(short)h1; ph[2]=(short)h2; ph[3]=(short)h3;
                pl[0]=(short)f2bf(v0-bf2f(h0)); pl[1]=(short)f2bf(v1-bf2f(h1));
                pl[2]=(short)f2bf(v2-bf2f(h2)); pl[3]=(short)f2bf(v3-bf2f(h3));
                *(short4v*)&aH[n * H1S + mbl] = ph;
                *(short4v*)&aL[n * H1S + mbl] = pl;
            }
        }
        __syncthreads();
        // conv4 partial: M=128 (wave: 2 mtiles x 8 ntiles), K=128 (this slice)
        for (int ks = 0; ks < 4; ++ks) {
            int ko = ks * 32 + lq * 8;
            short8 bh[8], bl[8];
            #pragma unroll
            for (int j = 0; j < 8; ++j) {
                bh[j] = *(const short8*)&aH[(j * 16 + lrow) * H1S + ko];
                bl[j] = *(const short8*)&aL[(j * 16 + lrow) * H1S + ko];
            }
            #pragma unroll
            for (int i = 0; i < 2; ++i) {
                int m = (wave * 2 + i) * 16 + lrow;
                short8 ah = *(const short8*)&w4hg[m * C3 + s * 128 + ko];
                short8 al = *(const short8*)&w4lg[m * C3 + s * 128 + ko];
                #pragma unroll
                for (int j = 0; j < 8; ++j) {
                    acc4[i][j] = MFMA16(ah, bh[j], acc4[i][j]);
                    acc4[i][j] = MFMA16(ah, bl[j], acc4[i][j]);
                    acc4[i][j] = MFMA16(al, bh[j], acc4[i][j]);
                }
            }
        }
    }

    // ---- max over 128 neighbors: over 8 ntiles in-register, then 16 n-lanes ----
    #pragma unroll
    for (int i = 0; i < 2; ++i) {
        #pragma unroll
        for (int r = 0; r < 4; ++r) {
            float v = -3.4e38f;
            #pragma unroll
            for (int j = 0; j < 8; ++j) v = fmaxf(v, acc4[i][j][r]);
            v = fmaxf(v, __shfl_xor(v, 1));
            v = fmaxf(v, __shfl_xor(v, 2));
            v = fmaxf(v, __shfl_xor(v, 4));
            v = fmaxf(v, __shfl_xor(v, 8));
            if (lrow == 0) fmaxbuf[(wave * 2 + i) * 16 + lq * 4 + r] = v;
        }
    }
    __syncthreads();
    if (t < C4) {
        float v = fmaxbuf[t] + b4[t];
        int b = blk >> 11, n = blk & (NPTS - 1);
        out[((size_t)b * C4 + t) * NPTS + n] = v;
    }
}

// ---------------------------------------------------------------------------
extern "C" void kernel_launch(void* const* d_in, const int* in_sizes, int n_in,
                              void* d_out, int out_size, void* d_ws, size_t ws_size,
                              hipStream_t stream) {
    const float* pos = (const float*)d_in[0];
    const float* w1  = (const float*)d_in[1];
    const float* b1  = (const float*)d_in[2];
    const float* g1  = (const float*)d_in[3];
    const float* be1 = (const float*)d_in[4];
    const float* w2  = (const float*)d_in[5];
    const float* b2  = (const float*)d_in[6];
    const float* w3  = (const float*)d_in[7];
    const float* b3  = (const float*)d_in[8];
    const float* g2  = (const float*)d_in[9];
    const float* be2 = (const float*)d_in[10];
    const float* w4  = (const float*)d_in[11];
    const float* b4  = (const float*)d_in[12];
    float* out = (float*)d_out;
    float* ws  = (float*)d_ws;

    float* gp      = ws;                          // 1572864
    float* w2t     = gp + 1572864;                // 32768
    float* w3t     = w2t + 32768;                 // 262144
    float* bn1sumr = w3t + 262144;                // 1024
    float* bn1sqr  = bn1sumr + NREP * C1;         // 1024
    float* bn2sumr = bn1sqr + NREP * C1;          // 4096
    float* bn2sqr  = bn2sumr + NREP * C3;         // 4096
    float* sc1     = bn2sqr + NREP * C3;          // 128
    float* sh1     = sc1 + 128;                   // 128
    float* sc2     = sh1 + 128;                   // 512
    float* sh2     = sc2 + 512;                   // 512
    float* c3buf   = sh2 + 512;                   // 4096*512 = 2097152
    unsigned short* uw = (unsigned short*)(c3buf + 2097152);
    unsigned short* w2hg = uw;                    // 32768
    unsigned short* w2lg = uw + 32768;            // 32768
    unsigned short* w3bh = uw + 65536;            // 131072
    unsigned short* w3bl = uw + 196608;           // 131072
    unsigned short* w4hg = uw + 327680;           // 65536
    unsigned short* w4lg = uw + 393216;           // 65536

    hipMemsetAsync(bn1sumr, 0, (size_t)(2 * NREP * C1 + 2 * NREP * C3) * sizeof(float), stream);
    prep_kernel<<<512, 256, 0, stream>>>(w2, w3, w4, w2t, w3t,
                                         w2hg, w2lg, w3bh, w3bl, w4hg, w4lg);
    knn_kernel<<<NGROUP, 256, 0, stream>>>(pos, w1, b1, out, gp, bn1sumr, bn1sqr);
    bn_finalize<<<1, 128, 0, stream>>>(bn1sumr, bn1sqr, g1, be1, sc1, sh1, C1, 1.f / 524288.f);
    stats2_kernel<<<NGROUP, 256, 0, stream>>>(gp, w1, b1, sc1, sh1, w2t, b2, w3t, b3,
                                              c3buf, bn2sumr, bn2sqr);
    bn_finalize<<<1, 512, 0, stream>>>(bn2sumr, bn2sqr, g2, be2, sc2, sh2, C3, 1.f / 524288.f);
    final_mfma_kernel<<<NGROUP, 256, 0, stream>>>(gp, w1, b1, sc1, sh1,
                                                  w2hg, w2lg, b2, w3bh, w3bl,
                                                  sc2, sh2, w4hg, w4lg, b4, c3buf, out);
}

// Round 6
// 1675.463 us; speedup vs baseline: 5.3840x; 1.8633x over previous
//
#include <hip/hip_runtime.h>
#include <stdint.h>

#define NPTS  2048
#define BATCH 2
#define KNN   128
#define C1    128
#define C2    256
#define C3    512
#define C4    128
#define NGROUP (BATCH * NPTS)    // 4096
#define FEAT_ELEMS (BATCH * C4 * NPTS)  // 524288
#define HBINS 2048
#define NREP  8

typedef short short8 __attribute__((ext_vector_type(8)));
typedef short short4v __attribute__((ext_vector_type(4)));
typedef float float4v __attribute__((ext_vector_type(4)));
#define MFMA16(a, b, c) __builtin_amdgcn_mfma_f32_16x16x32_bf16(a, b, c, 0, 0, 0)

__device__ __host__ inline unsigned short f2bf(float x) {
    unsigned u = __float_as_uint(x);
    return (unsigned short)((u + 0x7fffu + ((u >> 16) & 1u)) >> 16);
}
__device__ inline float bf2f(unsigned short s) {
    return __uint_as_float(((unsigned)s) << 16);
}

// ---------------------------------------------------------------------------
__global__ void prep_kernel(const float* __restrict__ w2, const float* __restrict__ w3,
                            const float* __restrict__ w4,
                            float* __restrict__ w3t,
                            unsigned short* __restrict__ w2hg, unsigned short* __restrict__ w2lg,
                            unsigned short* __restrict__ w3bh, unsigned short* __restrict__ w3bl,
                            unsigned short* __restrict__ w4hg, unsigned short* __restrict__ w4lg) {
    int tid = blockIdx.x * blockDim.x + threadIdx.x;
    int stride = gridDim.x * blockDim.x;
    for (int i = tid; i < C2 * C1; i += stride) {
        float v = w2[i];
        unsigned short h = f2bf(v);
        w2hg[i] = h; w2lg[i] = f2bf(v - bf2f(h));
    }
    for (int i = tid; i < C3 * C3; i += stride) w3t[(i & (C3 - 1)) * C3 + (i >> 9)] = w3[i];
    for (int i = tid; i < C3 * C2; i += stride) {
        int m = i >> 8, k = i & 255;
        float v = w3[m * C3 + C2 + k];
        unsigned short h = f2bf(v);
        w3bh[i] = h; w3bl[i] = f2bf(v - bf2f(h));
    }
    for (int i = tid; i < C4 * C3; i += stride) {
        float v = w4[i];
        unsigned short h = f2bf(v);
        w4hg[i] = h; w4lg[i] = f2bf(v - bf2f(h));
    }
}

// ---------------------------------------------------------------------------
// K0: exact kNN via 2-level radix select (bit-identical distance math) + BN1.
__launch_bounds__(256)
__global__ void knn_kernel(const float* __restrict__ pos,
                           const float* __restrict__ w1, const float* __restrict__ b1,
                           float* __restrict__ out,
                           float* __restrict__ gp,
                           float* __restrict__ bn1sumr, float* __restrict__ bn1sqr) {
    __shared__ float px[NPTS], py[NPTS], pz[NPTS];
    __shared__ unsigned int dbits[NPTS];
    __shared__ unsigned int hist[HBINS];
    __shared__ unsigned int seg[256];
    __shared__ unsigned long long cand[256];
    __shared__ float gsx[KNN], gsy[KNN], gsz[KNN];
    __shared__ float red[256];
    __shared__ unsigned int s_b1, s_c0, s_p22, s_cnt;

    int t = threadIdx.x;
    int blk = blockIdx.x;
    int b = blk >> 11, n = blk & (NPTS - 1);
    const float* pb = pos + (size_t)b * NPTS * 3;
    for (int i = t; i < NPTS; i += 256) {
        px[i] = pb[i * 3 + 0]; py[i] = pb[i * 3 + 1]; pz[i] = pb[i * 3 + 2];
    }
    for (int i = t; i < HBINS; i += 256) hist[i] = 0;
    if (t == 0) s_cnt = 0;
    __syncthreads();

    float qx = px[n], qy = py[n], qz = pz[n];
    {
        #pragma clang fp contract(off)
        float sqi = (qx * qx + qy * qy) + qz * qz;
        for (int j = t; j < NPTS; j += 256) {
            float xj = px[j], yj = py[j], zj = pz[j];
            float sqj = (xj * xj + yj * yj) + zj * zj;
            float dot = fmaf(qz, zj, fmaf(qy, yj, qx * xj));
            float d2 = (sqi + sqj) - 2.0f * dot;
            float dist = sqrtf(fmaxf(d2, 0.0f));
            unsigned int bits = __float_as_uint(dist);
            dbits[j] = bits;
            atomicAdd(&hist[bits >> 20], 1u);
        }
    }
    __syncthreads();
    {
        unsigned int s = 0;
        #pragma unroll
        for (int q = 0; q < 8; ++q) s += hist[t * 8 + q];
        seg[t] = s;
        __syncthreads();
        for (int off = 1; off < 256; off <<= 1) {
            unsigned int v = seg[t];
            unsigned int u = (t >= off) ? seg[t - off] : 0;
            __syncthreads();
            seg[t] = v + u;
            __syncthreads();
        }
        unsigned int before = (t == 0) ? 0u : seg[t - 1];
        unsigned int incl = seg[t];
        if (before <= 127u && 127u < incl) {
            unsigned int c = before;
            for (int q = 0; q < 8; ++q) {
                unsigned int h = hist[t * 8 + q];
                if (c + h > 127u) { s_b1 = t * 8 + q; s_c0 = c; break; }
                c += h;
            }
        }
    }
    __syncthreads();
    unsigned int B1 = s_b1, c0 = s_c0;
    for (int i = t; i < HBINS; i += 256) hist[i] = 0;
    __syncthreads();
    for (int j = t; j < NPTS; j += 256) {
        unsigned int bits = dbits[j];
        if ((bits >> 20) == B1) atomicAdd(&hist[(bits >> 9) & 0x7FFu], 1u);
    }
    __syncthreads();
    {
        unsigned int target = 127u - c0;
        unsigned int s = 0;
        #pragma unroll
        for (int q = 0; q < 8; ++q) s += hist[t * 8 + q];
        seg[t] = s;
        __syncthreads();
        for (int off = 1; off < 256; off <<= 1) {
            unsigned int v = seg[t];
            unsigned int u = (t >= off) ? seg[t - off] : 0;
            __syncthreads();
            seg[t] = v + u;
            __syncthreads();
        }
        unsigned int before = (t == 0) ? 0u : seg[t - 1];
        unsigned int incl = seg[t];
        if (before <= target && target < incl) {
            unsigned int c = before;
            for (int q = 0; q < 8; ++q) {
                unsigned int h = hist[t * 8 + q];
                if (c + h > target) { s_p22 = (B1 << 11) | (unsigned)(t * 8 + q); break; }
                c += h;
            }
        }
    }
    cand[t] = 0xFFFFFFFFFFFFFFFFull;
    __syncthreads();
    unsigned int P22 = s_p22;
    for (int j = t; j < NPTS; j += 256) {
        unsigned int bits = dbits[j];
        if ((bits >> 9) <= P22) {
            unsigned int pos_ = atomicAdd(&s_cnt, 1u);
            if (pos_ < 256u) cand[pos_] = ((unsigned long long)bits << 32) | (unsigned int)j;
        }
    }
    __syncthreads();
    for (int k2 = 2; k2 <= 256; k2 <<= 1) {
        for (int s2 = k2 >> 1; s2 > 0; s2 >>= 1) {
            int l = t ^ s2;
            if (l > t) {
                unsigned long long a = cand[t], c = cand[l];
                bool up = ((t & k2) == 0);
                if ((a > c) == up) { cand[t] = c; cand[l] = a; }
            }
            __syncthreads();
        }
    }
    if (t < KNN) {
        unsigned int j = (unsigned int)(cand[t] & 0xffffffffu);
        out[FEAT_ELEMS + (size_t)blk * KNN + t] = (float)j;
        float gx_ = px[j] - qx, gy_ = py[j] - qy, gz_ = pz[j] - qz;
        gsx[t] = gx_; gsy[t] = gy_; gsz[t] = gz_;
        float* g = gp + ((size_t)blk * KNN + t) * 3;
        g[0] = gx_; g[1] = gy_; g[2] = gz_;
    }
    __syncthreads();
    int c = t & (C1 - 1);
    int half = t >> 7;
    float wa = w1[c * 3 + 0], wb = w1[c * 3 + 1], wc = w1[c * 3 + 2], bc = b1[c];
    float s = 0.f, q = 0.f;
    for (int r = half * 64; r < half * 64 + 64; ++r) {
        float f = wa * gsx[r] + wb * gsy[r] + wc * gsz[r] + bc;
        s += f; q += f * f;
    }
    red[t] = s; __syncthreads();
    int rep = blk & (NREP - 1);
    if (t < C1) atomicAdd(bn1sumr + rep * C1 + t, red[t] + red[t + C1]);
    __syncthreads();
    red[t] = q; __syncthreads();
    if (t < C1) atomicAdd(bn1sqr + rep * C1 + t, red[t] + red[t + C1]);
}

// ---------------------------------------------------------------------------
__global__ void bn_finalize(const float* __restrict__ sumr, const float* __restrict__ sqr,
                            const float* __restrict__ g, const float* __restrict__ be,
                            float* __restrict__ scale, float* __restrict__ shift,
                            int nch, float inv_count) {
    int c = blockIdx.x * blockDim.x + threadIdx.x;
    if (c < nch) {
        float s = 0.f, q = 0.f;
        for (int r = 0; r < NREP; ++r) { s += sumr[r * nch + c]; q += sqr[r * nch + c]; }
        float m = s * inv_count;
        float v = fmaxf(q * inv_count - m * m, 0.f);
        float sc = g[c] / sqrtf(v + 1e-5f);
        scale[c] = sc;
        shift[c] = be[c] - m * sc;
    }
}

#define H1S 136   // h1/g3 row stride (shorts)
#define F2S 264   // f2 row stride (shorts)

// ---------------------------------------------------------------------------
// stats2 (MFMA): conv1 -> conv2 (hi/lo MFMA) -> fg (shfl-max) -> f2 bf16 LDS
// -> c3 matvec (fp32) -> conv3 in 4 m-slices (MFMA) -> BN2 moments via
// f3 = m + c3 decomposition, 8-way replicated atomics. Stores c3buf.
__launch_bounds__(256, 1)
__global__ void stats2_mfma_kernel(const float* __restrict__ gp,
                                   const float* __restrict__ w1, const float* __restrict__ b1,
                                   const float* __restrict__ sc1, const float* __restrict__ sh1,
                                   const unsigned short* __restrict__ w2hg, const unsigned short* __restrict__ w2lg,
                                   const float* __restrict__ b2,
                                   const float* __restrict__ w3t,
                                   const unsigned short* __restrict__ w3bh, const unsigned short* __restrict__ w3bl,
                                   const float* __restrict__ b3,
                                   float* __restrict__ c3buf,
                                   float* __restrict__ bn2sumr, float* __restrict__ bn2sqr) {
    __shared__ __align__(16) unsigned short ovl[2 * 128 * H1S];   // h1 hi/lo
    __shared__ __align__(16) unsigned short f2s[128 * F2S];       // f2 single bf16 [n][c2]
    __shared__ float gfl[KNN * 3];
    __shared__ float w1s[C1 * 3], b1s[C1], sc1s[C1], sh1s[C1], b2s[C2];
    __shared__ float fgs[C2];
    __shared__ float c3s[C3];

    unsigned short* aH = ovl;
    unsigned short* aL = ovl + 128 * H1S;

    int t = threadIdx.x, blk = blockIdx.x;
    int lane = t & 63, wave = t >> 6;
    int lrow = lane & 15, lq = lane >> 4;

    const float* g = gp + (size_t)blk * KNN * 3;
    for (int i = t; i < KNN * 3; i += 256) gfl[i] = g[i];
    for (int i = t; i < C1 * 3; i += 256) w1s[i] = w1[i];
    if (t < C1) { b1s[t] = b1[t]; sc1s[t] = sc1[t]; sh1s[t] = sh1[t]; }
    b2s[t] = b2[t];
    __syncthreads();

    // ---- conv1 + BN1 + ReLU -> h1 hi/lo ----
    {
        int n = t >> 1;
        int cb = (t & 1) * 64;
        float gx = gfl[n * 3], gy = gfl[n * 3 + 1], gz = gfl[n * 3 + 2];
        #pragma unroll
        for (int e8 = 0; e8 < 8; ++e8) {
            short8 vh, vl;
            #pragma unroll
            for (int e = 0; e < 8; ++e) {
                int c = cb + e8 * 8 + e;
                float f = w1s[c*3] * gx + w1s[c*3+1] * gy + w1s[c*3+2] * gz + b1s[c];
                float v = fmaxf(f * sc1s[c] + sh1s[c], 0.f);
                unsigned short h = f2bf(v);
                vh[e] = (short)h;
                vl[e] = (short)f2bf(v - bf2f(h));
            }
            *(short8*)&aH[n * H1S + cb + e8 * 8] = vh;
            *(short8*)&aL[n * H1S + cb + e8 * 8] = vl;
        }
    }
    __syncthreads();

    const float4v zero4 = {0.f, 0.f, 0.f, 0.f};

    // ---- conv2 MFMA: M=256, K=128, N=128 ----
    {
        float4v acc2[4][8];
        #pragma unroll
        for (int i = 0; i < 4; ++i)
            #pragma unroll
            for (int j = 0; j < 8; ++j) acc2[i][j] = zero4;
        for (int ks = 0; ks < 4; ++ks) {
            int ko = ks * 32 + lq * 8;
            short8 bh[8], bl[8];
            #pragma unroll
            for (int j = 0; j < 8; ++j) {
                bh[j] = *(const short8*)&aH[(j * 16 + lrow) * H1S + ko];
                bl[j] = *(const short8*)&aL[(j * 16 + lrow) * H1S + ko];
            }
            #pragma unroll
            for (int i = 0; i < 4; ++i) {
                int m = (wave * 4 + i) * 16 + lrow;
                short8 ah = *(const short8*)&w2hg[m * C1 + ko];
                short8 al = *(const short8*)&w2lg[m * C1 + ko];
                #pragma unroll
                for (int j = 0; j < 8; ++j) {
                    acc2[i][j] = MFMA16(ah, bh[j], acc2[i][j]);
                    acc2[i][j] = MFMA16(ah, bl[j], acc2[i][j]);
                    acc2[i][j] = MFMA16(al, bh[j], acc2[i][j]);
                }
            }
        }
        // epilogue: bias, fg (max over n), pack f2 single bf16
        #pragma unroll
        for (int i = 0; i < 4; ++i) {
            int mb = (wave * 4 + i) * 16 + lq * 4;
            float bb0 = b2s[mb], bb1 = b2s[mb+1], bb2 = b2s[mb+2], bb3 = b2s[mb+3];
            float mx0 = -3.4e38f, mx1 = -3.4e38f, mx2 = -3.4e38f, mx3 = -3.4e38f;
            #pragma unroll
            for (int j = 0; j < 8; ++j) {
                int n = j * 16 + lrow;
                float v0 = acc2[i][j][0] + bb0, v1 = acc2[i][j][1] + bb1;
                float v2 = acc2[i][j][2] + bb2, v3 = acc2[i][j][3] + bb3;
                short4v p;
                p[0] = (short)f2bf(v0); p[1] = (short)f2bf(v1);
                p[2] = (short)f2bf(v2); p[3] = (short)f2bf(v3);
                *(short4v*)&f2s[n * F2S + mb] = p;
                mx0 = fmaxf(mx0, v0); mx1 = fmaxf(mx1, v1);
                mx2 = fmaxf(mx2, v2); mx3 = fmaxf(mx3, v3);
            }
            float mx[4] = {mx0, mx1, mx2, mx3};
            #pragma unroll
            for (int r = 0; r < 4; ++r) {
                float v = mx[r];
                v = fmaxf(v, __shfl_xor(v, 1));
                v = fmaxf(v, __shfl_xor(v, 2));
                v = fmaxf(v, __shfl_xor(v, 4));
                v = fmaxf(v, __shfl_xor(v, 8));
                if (lrow == 0) fgs[mb + r] = v;
            }
        }
    }
    __syncthreads();

    // ---- c3 = b3 + W3a·fg (fp32) ----
    {
        float c3a = b3[t], c3b = b3[t + 256];
        for (int c2_ = 0; c2_ < C2; ++c2_) {
            float f = fgs[c2_];
            c3a += w3t[(size_t)c2_ * C3 + t] * f;
            c3b += w3t[(size_t)c2_ * C3 + t + 256] * f;
        }
        c3s[t] = c3a; c3s[t + 256] = c3b;
        c3buf[(size_t)blk * C3 + t] = c3a;
        c3buf[(size_t)blk * C3 + t + 256] = c3b;
    }
    __syncthreads();

    // ---- conv3 in 4 m-slices + BN2 moments ----
    int rep = blk & (NREP - 1);
    for (int s = 0; s < 4; ++s) {
        float4v acc3[2][8];
        #pragma unroll
        for (int i = 0; i < 2; ++i)
            #pragma unroll
            for (int j = 0; j < 8; ++j) acc3[i][j] = zero4;
        for (int ks = 0; ks < 8; ++ks) {
            int ko = ks * 32 + lq * 8;
            short8 bh[8];
            #pragma unroll
            for (int j = 0; j < 8; ++j)
                bh[j] = *(const short8*)&f2s[(j * 16 + lrow) * F2S + ko];
            #pragma unroll
            for (int i = 0; i < 2; ++i) {
                int mg = s * 128 + (wave * 2 + i) * 16 + lrow;
                short8 ah = *(const short8*)&w3bh[mg * C2 + ko];
                short8 al = *(const short8*)&w3bl[mg * C2 + ko];
                #pragma unroll
                for (int j = 0; j < 8; ++j) {
                    acc3[i][j] = MFMA16(ah, bh[j], acc3[i][j]);
                    acc3[i][j] = MFMA16(al, bh[j], acc3[i][j]);
                }
            }
        }
        #pragma unroll
        for (int i = 0; i < 2; ++i) {
            #pragma unroll
            for (int r = 0; r < 4; ++r) {
                float sS = 0.f, qS = 0.f;
                #pragma unroll
                for (int j = 0; j < 8; ++j) {
                    float v = acc3[i][j][r];
                    sS += v; qS += v * v;
                }
                sS += __shfl_xor(sS, 1); qS += __shfl_xor(qS, 1);
                sS += __shfl_xor(sS, 2); qS += __shfl_xor(qS, 2);
                sS += __shfl_xor(sS, 4); qS += __shfl_xor(qS, 4);
                sS += __shfl_xor(sS, 8); qS += __shfl_xor(qS, 8);
                if (lrow == 0) {
                    int mg = s * 128 + (wave * 2 + i) * 16 + lq * 4 + r;
                    float cc = c3s[mg];
                    atomicAdd(bn2sumr + rep * C3 + mg, sS + 128.f * cc);
                    atomicAdd(bn2sqr  + rep * C3 + mg, qS + 2.f * cc * sS + 128.f * cc * cc);
                }
            }
        }
    }
}

// ---------------------------------------------------------------------------
// final (MFMA, N=128): unchanged from round 5.
__launch_bounds__(256, 1)
__global__ void final_mfma_kernel(const float* __restrict__ gp,
                                  const float* __restrict__ w1, const float* __restrict__ b1,
                                  const float* __restrict__ sc1, const float* __restrict__ sh1,
                                  const unsigned short* __restrict__ w2hg, const unsigned short* __restrict__ w2lg,
                                  const float* __restrict__ b2,
                                  const unsigned short* __restrict__ w3bh, const unsigned short* __restrict__ w3bl,
                                  const float* __restrict__ sc2, const float* __restrict__ sh2,
                                  const unsigned short* __restrict__ w4hg, const unsigned short* __restrict__ w4lg,
                                  const float* __restrict__ b4,
                                  const float* __restrict__ c3buf, float* __restrict__ out) {
    __shared__ __align__(16) unsigned short ovl[2 * 128 * H1S];
    __shared__ __align__(16) unsigned short f2s[128 * F2S];
    __shared__ float gfl[KNN * 3];
    __shared__ float w1s[C1 * 3], b1s[C1], sc1s[C1], sh1s[C1], b2s[C2];
    __shared__ float c3s[C3], sc2s[C3], sh2s[C3];
    __shared__ float fmaxbuf[C4];

    unsigned short* aH = ovl;
    unsigned short* aL = ovl + 128 * H1S;

    int t = threadIdx.x, blk = blockIdx.x;
    int lane = t & 63, wave = t >> 6;
    int lrow = lane & 15, lq = lane >> 4;

    const float* g = gp + (size_t)blk * KNN * 3;
    for (int i = t; i < KNN * 3; i += 256) gfl[i] = g[i];
    for (int i = t; i < C1 * 3; i += 256) w1s[i] = w1[i];
    if (t < C1) { b1s[t] = b1[t]; sc1s[t] = sc1[t]; sh1s[t] = sh1[t]; }
    b2s[t] = b2[t];
    for (int i = t; i < C3; i += 256) {
        c3s[i] = c3buf[(size_t)blk * C3 + i];
        sc2s[i] = sc2[i]; sh2s[i] = sh2[i];
    }
    __syncthreads();

    {
        int n = t >> 1;
        int cb = (t & 1) * 64;
        float gx = gfl[n * 3], gy = gfl[n * 3 + 1], gz = gfl[n * 3 + 2];
        #pragma unroll
        for (int e8 = 0; e8 < 8; ++e8) {
            short8 vh, vl;
            #pragma unroll
            for (int e = 0; e < 8; ++e) {
                int c = cb + e8 * 8 + e;
                float f = w1s[c*3] * gx + w1s[c*3+1] * gy + w1s[c*3+2] * gz + b1s[c];
                float v = fmaxf(f * sc1s[c] + sh1s[c], 0.f);
                unsigned short h = f2bf(v);
                vh[e] = (short)h;
                vl[e] = (short)f2bf(v - bf2f(h));
            }
            *(short8*)&aH[n * H1S + cb + e8 * 8] = vh;
            *(short8*)&aL[n * H1S + cb + e8 * 8] = vl;
        }
    }
    __syncthreads();

    const float4v zero4 = {0.f, 0.f, 0.f, 0.f};

    {
        float4v acc2[4][8];
        #pragma unroll
        for (int i = 0; i < 4; ++i)
            #pragma unroll
            for (int j = 0; j < 8; ++j) acc2[i][j] = zero4;
        for (int ks = 0; ks < 4; ++ks) {
            int ko = ks * 32 + lq * 8;
            short8 bh[8], bl[8];
            #pragma unroll
            for (int j = 0; j < 8; ++j) {
                bh[j] = *(const short8*)&aH[(j * 16 + lrow) * H1S + ko];
                bl[j] = *(const short8*)&aL[(j * 16 + lrow) * H1S + ko];
            }
            #pragma unroll
            for (int i = 0; i < 4; ++i) {
                int m = (wave * 4 + i) * 16 + lrow;
                short8 ah = *(const short8*)&w2hg[m * C1 + ko];
                short8 al = *(const short8*)&w2lg[m * C1 + ko];
                #pragma unroll
                for (int j = 0; j < 8; ++j) {
                    acc2[i][j] = MFMA16(ah, bh[j], acc2[i][j]);
                    acc2[i][j] = MFMA16(ah, bl[j], acc2[i][j]);
                    acc2[i][j] = MFMA16(al, bh[j], acc2[i][j]);
                }
            }
        }
        __syncthreads();
        #pragma unroll
        for (int i = 0; i < 4; ++i) {
            int mb = (wave * 4 + i) * 16 + lq * 4;
            float bb0 = b2s[mb], bb1 = b2s[mb+1], bb2 = b2s[mb+2], bb3 = b2s[mb+3];
            #pragma unroll
            for (int j = 0; j < 8; ++j) {
                int n = j * 16 + lrow;
                short4v p;
                p[0] = (short)f2bf(acc2[i][j][0] + bb0);
                p[1] = (short)f2bf(acc2[i][j][1] + bb1);
                p[2] = (short)f2bf(acc2[i][j][2] + bb2);
                p[3] = (short)f2bf(acc2[i][j][3] + bb3);
                *(short4v*)&f2s[n * F2S + mb] = p;
            }
        }
    }
    __syncthreads();

    float4v acc4[2][8];
    #pragma unroll
    for (int i = 0; i < 2; ++i)
        #pragma unroll
        for (int j = 0; j < 8; ++j) acc4[i][j] = zero4;

    for (int s = 0; s < 4; ++s) {
        float4v acc3[2][8];
        #pragma unroll
        for (int i = 0; i < 2; ++i)
            #pragma unroll
            for (int j = 0; j < 8; ++j) acc3[i][j] = zero4;
        for (int ks = 0; ks < 8; ++ks) {
            int ko = ks * 32 + lq * 8;
            short8 bh[8];
            #pragma unroll
            for (int j = 0; j < 8; ++j)
                bh[j] = *(const short8*)&f2s[(j * 16 + lrow) * F2S + ko];
            #pragma unroll
            for (int i = 0; i < 2; ++i) {
                int mg = s * 128 + (wave * 2 + i) * 16 + lrow;
                short8 ah = *(const short8*)&w3bh[mg * C2 + ko];
                short8 al = *(const short8*)&w3bl[mg * C2 + ko];
                #pragma unroll
                for (int j = 0; j < 8; ++j) {
                    acc3[i][j] = MFMA16(ah, bh[j], acc3[i][j]);
                    acc3[i][j] = MFMA16(al, bh[j], acc3[i][j]);
                }
            }
        }
        __syncthreads();
        #pragma unroll
        for (int i = 0; i < 2; ++i) {
            int mbl = (wave * 2 + i) * 16 + lq * 4;
            int mg  = s * 128 + mbl;
            float cA0 = c3s[mg],   sA0 = sc2s[mg],   hA0 = sh2s[mg];
            float cA1 = c3s[mg+1], sA1 = sc2s[mg+1], hA1 = sh2s[mg+1];
            float cA2 = c3s[mg+2], sA2 = sc2s[mg+2], hA2 = sh2s[mg+2];
            float cA3 = c3s[mg+3], sA3 = sc2s[mg+3], hA3 = sh2s[mg+3];
            #pragma unroll
            for (int j = 0; j < 8; ++j) {
                int n = j * 16 + lrow;
                float v0 = fmaxf((acc3[i][j][0] + cA0) * sA0 + hA0, 0.f);
                float v1 = fmaxf((acc3[i][j][1] + cA1) * sA1 + hA1, 0.f);
                float v2 = fmaxf((acc3[i][j][2] + cA2) * sA2 + hA2, 0.f);
                float v3 = fmaxf((acc3[i][j][3] + cA3) * sA3 + hA3, 0.f);
                short4v ph, pl;
                unsigned short h0 = f2bf(v0), h1 = f2bf(v1), h2 = f2bf(v2), h3 = f2bf(v3);
                ph[0]=(short)h0; ph[1]=(short)h1; ph[2]=(short)h2; ph[3]=(short)h3;
                pl[0]=(short)f2bf(v0-bf2f(h0)); pl[1]=(short)f2bf(v1-bf2f(h1));
                pl[2]=(short)f2bf(v2-bf2f(h2)); pl[3]=(short)f2bf(v3-bf2f(h3));
                *(short4v*)&aH[n * H1S + mbl] = ph;
                *(short4v*)&aL[n * H1S + mbl] = pl;
            }
        }
        __syncthreads();
        for (int ks = 0; ks < 4; ++ks) {
            int ko = ks * 32 + lq * 8;
            short8 bh[8], bl[8];
            #pragma unroll
            for (int j = 0; j < 8; ++j) {
                bh[j] = *(const short8*)&aH[(j * 16 + lrow) * H1S + ko];
                bl[j] = *(const short8*)&aL[(j * 16 + lrow) * H1S + ko];
            }
            #pragma unroll
            for (int i = 0; i < 2; ++i) {
                int m = (wave * 2 + i) * 16 + lrow;
                short8 ah = *(const short8*)&w4hg[m * C3 + s * 128 + ko];
                short8 al = *(const short8*)&w4lg[m * C3 + s * 128 + ko];
                #pragma unroll
                for (int j = 0; j < 8; ++j) {
                    acc4[i][j] = MFMA16(ah, bh[j], acc4[i][j]);
                    acc4[i][j] = MFMA16(ah, bl[j], acc4[i][j]);
                    acc4[i][j] = MFMA16(al, bh[j], acc4[i][j]);
                }
            }
        }
    }

    #pragma unroll
    for (int i = 0; i < 2; ++i) {
        #pragma unroll
        for (int r = 0; r < 4; ++r) {
            float v = -3.4e38f;
            #pragma unroll
            for (int j = 0; j < 8; ++j) v = fmaxf(v, acc4[i][j][r]);
            v = fmaxf(v, __shfl_xor(v, 1));
            v = fmaxf(v, __shfl_xor(v, 2));
            v = fmaxf(v, __shfl_xor(v, 4));
            v = fmaxf(v, __shfl_xor(v, 8));
            if (lrow == 0) fmaxbuf[(wave * 2 + i) * 16 + lq * 4 + r] = v;
        }
    }
    __syncthreads();
    if (t < C4) {
        float v = fmaxbuf[t] + b4[t];
        int b = blk >> 11, n = blk & (NPTS - 1);
        out[((size_t)b * C4 + t) * NPTS + n] = v;
    }
}

// ---------------------------------------------------------------------------
extern "C" void kernel_launch(void* const* d_in, const int* in_sizes, int n_in,
                              void* d_out, int out_size, void* d_ws, size_t ws_size,
                              hipStream_t stream) {
    const float* pos = (const float*)d_in[0];
    const float* w1  = (const float*)d_in[1];
    const float* b1  = (const float*)d_in[2];
    const float* g1  = (const float*)d_in[3];
    const float* be1 = (const float*)d_in[4];
    const float* w2  = (const float*)d_in[5];
    const float* b2  = (const float*)d_in[6];
    const float* w3  = (const float*)d_in[7];
    const float* b3  = (const float*)d_in[8];
    const float* g2  = (const float*)d_in[9];
    const float* be2 = (const float*)d_in[10];
    const float* w4  = (const float*)d_in[11];
    const float* b4  = (const float*)d_in[12];
    float* out = (float*)d_out;
    float* ws  = (float*)d_ws;

    float* gp      = ws;                          // 1572864
    float* w3t     = gp + 1572864;                // 262144
    float* bn1sumr = w3t + 262144;                // 1024
    float* bn1sqr  = bn1sumr + NREP * C1;         // 1024
    float* bn2sumr = bn1sqr + NREP * C1;          // 4096
    float* bn2sqr  = bn2sumr + NREP * C3;         // 4096
    float* sc1     = bn2sqr + NREP * C3;          // 128
    float* sh1     = sc1 + 128;                   // 128
    float* sc2     = sh1 + 128;                   // 512
    float* sh2     = sc2 + 512;                   // 512
    float* c3buf   = sh2 + 512;                   // 4096*512 = 2097152
    unsigned short* uw = (unsigned short*)(c3buf + 2097152);
    unsigned short* w2hg = uw;                    // 32768
    unsigned short* w2lg = uw + 32768;            // 32768
    unsigned short* w3bh = uw + 65536;            // 131072
    unsigned short* w3bl = uw + 196608;           // 131072
    unsigned short* w4hg = uw + 327680;           // 65536
    unsigned short* w4lg = uw + 393216;           // 65536

    hipMemsetAsync(bn1sumr, 0, (size_t)(2 * NREP * C1 + 2 * NREP * C3) * sizeof(float), stream);
    prep_kernel<<<512, 256, 0, stream>>>(w2, w3, w4, w3t,
                                         w2hg, w2lg, w3bh, w3bl, w4hg, w4lg);
    knn_kernel<<<NGROUP, 256, 0, stream>>>(pos, w1, b1, out, gp, bn1sumr, bn1sqr);
    bn_finalize<<<1, 128, 0, stream>>>(bn1sumr, bn1sqr, g1, be1, sc1, sh1, C1, 1.f / 524288.f);
    stats2_mfma_kernel<<<NGROUP, 256, 0, stream>>>(gp, w1, b1, sc1, sh1,
                                                   w2hg, w2lg, b2, w3t, w3bh, w3bl, b3,
                                                   c3buf, bn2sumr, bn2sqr);
    bn_finalize<<<1, 512, 0, stream>>>(bn2sumr, bn2sqr, g2, be2, sc2, sh2, C3, 1.f / 524288.f);
    final_mfma_kernel<<<NGROUP, 256, 0, stream>>>(gp, w1, b1, sc1, sh1,
                                                  w2hg, w2lg, b2, w3bh, w3bl,
                                                  sc2, sh2, w4hg, w4lg, b4, c3buf, out);
}